// Round 4
// baseline (264.834 us; speedup 1.0000x reference)
//
#include <hip/hip_runtime.h>
#include <math.h>

#define NT 16384     // tokens
#define NE 4096      // embed
#define NX 64        // experts
#define TK 8         // top-k

#define BM 32
#define NBLK (NT / BM)        // 512 blocks
#define KRANGE 1024           // K-range per kg-wave-group
#define NSTEP (KRANGE / 32)   // 32 k-steps

#define RO_SIZE (NT * NX)
#define TI_OFF  RO_SIZE
#define AUX_IDX (RO_SIZE + NT * TK)

#define MAXFLAG 8192
#define STATS_FLOATS (130 + MAXFLAG)
#define BPACK_OFF ((((STATS_FLOATS * 4) + 255) / 256) * 256)
#define BPACK_USHORTS (128 * 4 * 2 * 128 * 8)   // kt x kq x h x col x 8 = 1M ushorts (2MB)
#define WS_NEED ((size_t)BPACK_OFF + (size_t)BPACK_USHORTS * 2)

#define DELTA_FP32 5e-5f
#define DELTA_BF16 2.5e-4f   // bf16x3 sigma ~1.5e-5, 17-sigma margin (verified r2/r3)

typedef __attribute__((ext_vector_type(8))) short bf16x8_t;
typedef __attribute__((ext_vector_type(4))) float f32x4_t;

__device__ __forceinline__ float neginf() { return __int_as_float(0xff800000); }

__device__ __forceinline__ unsigned short bf16_trunc(float f) {
    return (unsigned short)(__float_as_uint(f) >> 16);
}
__device__ __forceinline__ unsigned short bf16_rtn(float f) {
    unsigned u = __float_as_uint(f);
    unsigned r = u + 0x7fffu + ((u >> 16) & 1u);
    return (unsigned short)(r >> 16);
}
__device__ __forceinline__ float bf16_to_f(unsigned short h) {
    return __uint_as_float(((unsigned)h) << 16);
}

__device__ __forceinline__ void split8(const float4& a, const float4& b,
                                       bf16x8_t& h, bf16x8_t& l) {
    float f[8] = {a.x, a.y, a.z, a.w, b.x, b.y, b.z, b.w};
    #pragma unroll
    for (int j = 0; j < 8; ++j) {
        unsigned short hh = bf16_trunc(f[j]);
        h[j] = (short)hh;
        l[j] = (short)bf16_rtn(f[j] - bf16_to_f(hh));
    }
}

// ---------------------------------------------------------------------------
// prep: pack w_route|w_noise into fragment-major hi/lo bf16:
// chunk(kt,kq,h,col) = ((kt*4+kq)*2 + h)*128 + col, 8 ushorts per chunk.
// grid 128 (kt), 512 threads: thread -> (col = t&127, kq = t>>7)
// ---------------------------------------------------------------------------
__global__ __launch_bounds__(512) void prep_w_kernel(
    const float* __restrict__ w_route, const float* __restrict__ w_noise,
    unsigned short* __restrict__ bp)
{
    const int kt = blockIdx.x;
    const int t = threadIdx.x;
    const int col = t & 127;
    const int kq = t >> 7;
    const float* src = (col < NX) ? (w_route + col) : (w_noise + (col - NX));
    const int kbase = kt * 32 + kq * 8;
    bf16x8_t h8, l8;
    #pragma unroll
    for (int i = 0; i < 8; ++i) {
        float v = src[(size_t)(kbase + i) * NX];
        unsigned short hh = bf16_trunc(v);
        h8[i] = (short)hh;
        l8[i] = (short)bf16_rtn(v - bf16_to_f(hh));
    }
    unsigned short* base = bp + ((size_t)((kt * 4 + kq) * 2) * 128 + col) * 8;
    *(bf16x8_t*)base = h8;                 // h = 0
    *(bf16x8_t*)(base + 128 * 8) = l8;     // h = 1
}

// ---------------------------------------------------------------------------
// Fused barrier-free GEMM + routing.
// grid 512, 512 thr (8 waves = cg{2} x kg{4}); wave: 32 rows x 64 cols x K=1024.
// ---------------------------------------------------------------------------
__global__ __launch_bounds__(512, 4) void fused32_kernel(
    const float* __restrict__ x,
    const unsigned short* __restrict__ bp,
    const float* __restrict__ b_route, const float* __restrict__ b_noise,
    const float* __restrict__ noise,
    float* __restrict__ out,
    float* __restrict__ ps_acc, float* __restrict__ fr_acc,
    float* __restrict__ lse2_acc,
    int* __restrict__ flag_cnt, int* __restrict__ flag_list)
{
    __shared__ float part[4][32][130];   // 66,560 B; +2 col pad kills write conflicts

    const int tid = threadIdx.x;
    const int wid = tid >> 6;
    const int lane = tid & 63;
    const int l15 = lane & 15;
    const int kq = lane >> 4;          // k-quarter within a 32-k step
    const int kg = wid >> 1;           // K-range group (0..3)
    const int cg = wid & 1;            // col half (0..1)
    const int bm = blockIdx.x * BM;

    f32x4_t acc[2][4];
    #pragma unroll
    for (int r = 0; r < 2; ++r)
        #pragma unroll
        for (int c = 0; c < 4; ++c)
            acc[r][c] = (f32x4_t){0.f, 0.f, 0.f, 0.f};

    const float* pa0 = x + (size_t)(bm + l15) * NE + kg * KRANGE + kq * 8;
    const float* pa1 = pa0 + (size_t)16 * NE;
    const unsigned short* pb = bp
        + ((size_t)((kg * NSTEP * 4 + kq) * 2) * 128 + cg * 64 + l15) * 8;

    for (int t = 0; t < NSTEP; ++t) {
        float4 a00 = *(const float4*)pa0;
        float4 a01 = *(const float4*)(pa0 + 4);
        float4 a10 = *(const float4*)pa1;
        float4 a11 = *(const float4*)(pa1 + 4);
        bf16x8_t bh[4], bl[4];
        #pragma unroll
        for (int c = 0; c < 4; ++c) {
            bh[c] = *(const bf16x8_t*)(pb + c * 128);          // 16 cols stride
            bl[c] = *(const bf16x8_t*)(pb + 1024 + c * 128);
        }
        bf16x8_t ah0, al0, ah1, al1;
        split8(a00, a01, ah0, al0);
        split8(a10, a11, ah1, al1);
        #pragma unroll
        for (int c = 0; c < 4; ++c) {
            acc[0][c] = __builtin_amdgcn_mfma_f32_16x16x32_bf16(ah0, bh[c], acc[0][c], 0, 0, 0);
            acc[0][c] = __builtin_amdgcn_mfma_f32_16x16x32_bf16(ah0, bl[c], acc[0][c], 0, 0, 0);
            acc[0][c] = __builtin_amdgcn_mfma_f32_16x16x32_bf16(al0, bh[c], acc[0][c], 0, 0, 0);
            acc[1][c] = __builtin_amdgcn_mfma_f32_16x16x32_bf16(ah1, bh[c], acc[1][c], 0, 0, 0);
            acc[1][c] = __builtin_amdgcn_mfma_f32_16x16x32_bf16(ah1, bl[c], acc[1][c], 0, 0, 0);
            acc[1][c] = __builtin_amdgcn_mfma_f32_16x16x32_bf16(al1, bh[c], acc[1][c], 0, 0, 0);
        }
        pa0 += 32; pa1 += 32;
        pb += 4 * 2 * 128 * 8;   // next k-tile
    }

    // K-partials to LDS (C/D map: col=lane&15, row=(lane>>4)*4+j — verified r2/r3)
    #pragma unroll
    for (int r = 0; r < 2; ++r)
        #pragma unroll
        for (int c = 0; c < 4; ++c)
            #pragma unroll
            for (int j = 0; j < 4; ++j) {
                int tok = r * 16 + (lane >> 4) * 4 + j;
                int col = cg * 64 + c * 16 + l15;
                part[kg][tok][col] = acc[r][c][j];
            }
    __syncthreads();

    // ---- routing epilogue (verified r1-r3): 8 waves x 4 tokens ----
    const float br = b_route[lane];
    const float bnv = b_noise[lane];
    float ps_l = 0.f, fr_l = 0.f, l2_l = 0.f;

    for (int tt = 0; tt < 4; ++tt) {
        const int tok = wid * 4 + tt;
        const int gt  = bm + tok;
        float lr = part[0][tok][lane] + part[1][tok][lane]
                 + part[2][tok][lane] + part[3][tok][lane] + br;
        float ln = part[0][tok][64 + lane] + part[1][tok][64 + lane]
                 + part[2][tok][64 + lane] + part[3][tok][64 + lane] + bnv;
        float nz = noise[(size_t)gt * NX + lane];
        float sp = fmaxf(ln, 0.f) + log1pf(expf(-fabsf(ln)));   // softplus
        float v  = lr + nz * sp;                                 // noisy logit

        // top-9 iterative wave argmax (ties -> lower index)
        float vv = v;
        float tv[9]; int ti[9];
        #pragma unroll
        for (int s = 0; s < 9; ++s) {
            float mv = vv; int mi = lane;
            #pragma unroll
            for (int off = 32; off > 0; off >>= 1) {
                float ov = __shfl_xor(mv, off);
                int   oi = __shfl_xor(mi, off);
                if (ov > mv || (ov == mv && oi < mi)) { mv = ov; mi = oi; }
            }
            tv[s] = mv; ti[s] = mi;
            if (lane == mi) vv = neginf();
        }

        float ming = 1e30f;
        #pragma unroll
        for (int s = 0; s < 8; ++s) ming = fminf(ming, tv[s] - tv[s + 1]);
        if (lane == 0 && ming < DELTA_BF16) {
            int p = atomicAdd(flag_cnt, 1);
            if (p < MAXFLAG) flag_list[p] = gt;
        }

        const float m0 = tv[0];
        float e8[8], s8 = 0.f;
        #pragma unroll
        for (int s = 0; s < 8; ++s) { e8[s] = expf(tv[s] - m0); s8 += e8[s]; }
        float r = 0.f;
        #pragma unroll
        for (int s = 0; s < 8; ++s) if (ti[s] == lane) r = e8[s] / s8;
        out[(size_t)gt * NX + lane] = r;
        if (lane < TK) out[TI_OFF + (size_t)gt * TK + lane] = (float)ti[lane];

        float p = expf(v - m0);
        float s64 = p;
        #pragma unroll
        for (int off = 32; off > 0; off >>= 1) s64 += __shfl_xor(s64, off);
        ps_l += p / s64;
        if (lane == 0) { float lse = m0 + logf(s64); l2_l += lse * lse; }

        unsigned tm8 = 0;
        #pragma unroll
        for (int s = 0; s < 8; ++s) if (ti[s] < TK) tm8 |= (1u << ti[s]);
        #pragma unroll
        for (int s = 0; s < 8; ++s)
            if (ti[s] == lane && ((tm8 >> s) & 1u)) fr_l += 1.f;
    }
    atomicAdd(&ps_acc[lane], ps_l);
    atomicAdd(&fr_acc[lane], fr_l);
    if (lane == 0) atomicAdd(lse2_acc, l2_l);
}

// ---------------------------------------------------------------------------
// Fallback fp32-VALU fused kernel (round-1 verified) for small ws_size
// ---------------------------------------------------------------------------
#define FBM 64
#define FBN 128
#define FBK 32
#define XPITCH (FBM + 4)
__global__ __launch_bounds__(256) void fused_router_kernel(
    const float* __restrict__ x,
    const float* __restrict__ w_route, const float* __restrict__ b_route,
    const float* __restrict__ w_noise, const float* __restrict__ b_noise,
    const float* __restrict__ noise,
    float* __restrict__ out,
    float* __restrict__ ps_acc, float* __restrict__ fr_acc,
    float* __restrict__ lse2_acc,
    int* __restrict__ flag_cnt, int* __restrict__ flag_list)
{
    __shared__ float smem[FBM * FBN];
    float* xs  = smem;
    float* wst = smem + FBK * XPITCH;
    const int tid = threadIdx.x;
    const int block_m = blockIdx.x * FBM;
    const int row0 = (tid >> 5) * 8;
    const int col0 = (tid & 31) * 4;
    float acc[8][4];
    #pragma unroll
    for (int i = 0; i < 8; ++i)
        #pragma unroll
        for (int j = 0; j < 4; ++j) acc[i][j] = 0.f;
    float4 px[2], pw[4];
    {
        #pragma unroll
        for (int s = 0; s < 2; ++s) {
            int f = tid + s * 256, r = f >> 3, kqv = f & 7;
            px[s] = *reinterpret_cast<const float4*>(x + (size_t)(block_m + r) * NE + kqv * 4);
        }
        #pragma unroll
        for (int s = 0; s < 4; ++s) {
            int f = tid + s * 256, kk = f >> 5, c4 = (f & 31) * 4;
            const float* src = (c4 < NX) ? (w_route + (size_t)kk * NX + c4)
                                         : (w_noise + (size_t)kk * NX + (c4 - NX));
            pw[s] = *reinterpret_cast<const float4*>(src);
        }
    }
    for (int t = 0; t < NE / FBK; ++t) {
        __syncthreads();
        #pragma unroll
        for (int s = 0; s < 2; ++s) {
            int f = tid + s * 256, r = f >> 3, kqv = f & 7;
            xs[(kqv * 4 + 0) * XPITCH + r] = px[s].x;
            xs[(kqv * 4 + 1) * XPITCH + r] = px[s].y;
            xs[(kqv * 4 + 2) * XPITCH + r] = px[s].z;
            xs[(kqv * 4 + 3) * XPITCH + r] = px[s].w;
        }
        #pragma unroll
        for (int s = 0; s < 4; ++s) {
            int f = tid + s * 256, kk = f >> 5, c4 = (f & 31) * 4;
            *reinterpret_cast<float4*>(&wst[kk * FBN + c4]) = pw[s];
        }
        __syncthreads();
        if (t + 1 < NE / FBK) {
            const int k0 = (t + 1) * FBK;
            #pragma unroll
            for (int s = 0; s < 2; ++s) {
                int f = tid + s * 256, r = f >> 3, kqv = f & 7;
                px[s] = *reinterpret_cast<const float4*>(x + (size_t)(block_m + r) * NE + k0 + kqv * 4);
            }
            #pragma unroll
            for (int s = 0; s < 4; ++s) {
                int f = tid + s * 256, kk = f >> 5, c4 = (f & 31) * 4;
                const float* src = (c4 < NX) ? (w_route + (size_t)(k0 + kk) * NX + c4)
                                             : (w_noise + (size_t)(k0 + kk) * NX + (c4 - NX));
                pw[s] = *reinterpret_cast<const float4*>(src);
            }
        }
        #pragma unroll
        for (int k = 0; k < FBK; ++k) {
            float4 xa = *reinterpret_cast<const float4*>(&xs[k * XPITCH + row0]);
            float4 xb = *reinterpret_cast<const float4*>(&xs[k * XPITCH + row0 + 4]);
            float4 wv = *reinterpret_cast<const float4*>(&wst[k * FBN + col0]);
            float xf[8] = {xa.x, xa.y, xa.z, xa.w, xb.x, xb.y, xb.z, xb.w};
            float wf[4] = {wv.x, wv.y, wv.z, wv.w};
            #pragma unroll
            for (int i = 0; i < 8; ++i)
                #pragma unroll
                for (int j = 0; j < 4; ++j)
                    acc[i][j] = fmaf(xf[i], wf[j], acc[i][j]);
        }
    }
    __syncthreads();
    #pragma unroll
    for (int i = 0; i < 8; ++i) {
        float4 v = make_float4(acc[i][0], acc[i][1], acc[i][2], acc[i][3]);
        *reinterpret_cast<float4*>(&smem[(row0 + i) * FBN + col0]) = v;
    }
    __syncthreads();
    const int wave = tid >> 6;
    const int lane = tid & 63;
    const float br = b_route[lane];
    const float bnv = b_noise[lane];
    float ps_l = 0.f, fr_l = 0.f, l2_l = 0.f;
    for (int tt = 0; tt < FBM / 4; ++tt) {
        const int tok = wave * (FBM / 4) + tt;
        const int gt  = block_m + tok;
        float lr = smem[tok * FBN + lane] + br;
        float ln = smem[tok * FBN + NX + lane] + bnv;
        float nz = noise[(size_t)gt * NX + lane];
        float sp = fmaxf(ln, 0.f) + log1pf(expf(-fabsf(ln)));
        float v  = lr + nz * sp;
        float vv = v;
        float tv[9]; int ti[9];
        #pragma unroll
        for (int s = 0; s < 9; ++s) {
            float mv = vv; int mi = lane;
            #pragma unroll
            for (int off = 32; off > 0; off >>= 1) {
                float ov = __shfl_xor(mv, off);
                int   oi = __shfl_xor(mi, off);
                if (ov > mv || (ov == mv && oi < mi)) { mv = ov; mi = oi; }
            }
            tv[s] = mv; ti[s] = mi;
            if (lane == mi) vv = neginf();
        }
        float ming = 1e30f;
        #pragma unroll
        for (int s = 0; s < 8; ++s) ming = fminf(ming, tv[s] - tv[s + 1]);
        if (lane == 0 && ming < DELTA_FP32) {
            int p = atomicAdd(flag_cnt, 1);
            if (p < MAXFLAG) flag_list[p] = gt;
        }
        const float m0 = tv[0];
        float e8[8], s8 = 0.f;
        #pragma unroll
        for (int s = 0; s < 8; ++s) { e8[s] = expf(tv[s] - m0); s8 += e8[s]; }
        float r = 0.f;
        #pragma unroll
        for (int s = 0; s < 8; ++s) if (ti[s] == lane) r = e8[s] / s8;
        out[(size_t)gt * NX + lane] = r;
        if (lane < TK) out[TI_OFF + (size_t)gt * TK + lane] = (float)ti[lane];
        float p = expf(v - m0);
        float s64 = p;
        #pragma unroll
        for (int off = 32; off > 0; off >>= 1) s64 += __shfl_xor(s64, off);
        ps_l += p / s64;
        if (lane == 0) { float lse = m0 + logf(s64); l2_l += lse * lse; }
        unsigned tm8 = 0;
        #pragma unroll
        for (int s = 0; s < 8; ++s) if (ti[s] < TK) tm8 |= (1u << ti[s]);
        #pragma unroll
        for (int s = 0; s < 8; ++s)
            if (ti[s] == lane && ((tm8 >> s) & 1u)) fr_l += 1.f;
    }
    atomicAdd(&ps_acc[lane], ps_l);
    atomicAdd(&fr_acc[lane], fr_l);
    if (lane == 0) atomicAdd(lse2_acc, l2_l);
}

// ---------------------------------------------------------------------------
// fp64 repair of near-tie tokens (verified r3)
// ---------------------------------------------------------------------------
__global__ __launch_bounds__(256) void refine_kernel(
    const float* __restrict__ x, const float* __restrict__ w_route,
    const float* __restrict__ b_route, const float* __restrict__ w_noise,
    const float* __restrict__ b_noise, const float* __restrict__ noise,
    float* __restrict__ out, const int* __restrict__ flag_cnt,
    const int* __restrict__ flag_list)
{
    __shared__ double red[8][64];
    const int tid = threadIdx.x;
    const int lane = tid & 63, wq = tid >> 6;
    int nf = *flag_cnt; if (nf > MAXFLAG) nf = MAXFLAG;
    for (int fi = blockIdx.x; fi < nf; fi += gridDim.x) {
        const int gt = flag_list[fi];
        const float* xr = x + (size_t)gt * NE + wq * 1024;
        const float* wr = w_route + (size_t)wq * 1024 * NX;
        const float* wn = w_noise + (size_t)wq * 1024 * NX;
        double ar0 = 0, ar1 = 0, an0 = 0, an1 = 0;
        for (int k = 0; k < 1024; k += 2) {
            double x0 = xr[k], x1 = xr[k + 1];
            ar0 += x0 * (double)wr[(size_t)k * NX + lane];
            ar1 += x1 * (double)wr[(size_t)(k + 1) * NX + lane];
            an0 += x0 * (double)wn[(size_t)k * NX + lane];
            an1 += x1 * (double)wn[(size_t)(k + 1) * NX + lane];
        }
        red[wq * 2][lane]     = ar0 + ar1;
        red[wq * 2 + 1][lane] = an0 + an1;
        __syncthreads();
        if (tid < 64) {
            double lr = red[0][lane] + red[2][lane] + red[4][lane] + red[6][lane]
                      + (double)b_route[lane];
            double ln = red[1][lane] + red[3][lane] + red[5][lane] + red[7][lane]
                      + (double)b_noise[lane];
            double nz = (double)noise[(size_t)gt * NX + lane];
            double sp = (ln > 0.0) ? (ln + log1p(exp(-ln))) : log1p(exp(ln));
            double v  = lr + nz * sp;
            double vv = v;
            double tv[8]; int ti[8];
            #pragma unroll
            for (int s = 0; s < 8; ++s) {
                double mv = vv; int mi = lane;
                #pragma unroll
                for (int off = 32; off > 0; off >>= 1) {
                    double ov = __shfl_xor(mv, off);
                    int    oi = __shfl_xor(mi, off);
                    if (ov > mv || (ov == mv && oi < mi)) { mv = ov; mi = oi; }
                }
                tv[s] = mv; ti[s] = mi;
                if (lane == mi) vv = -1.0e300;
            }
            double m0 = tv[0], s8 = 0.0, e8[8];
            #pragma unroll
            for (int s = 0; s < 8; ++s) { e8[s] = exp(tv[s] - m0); s8 += e8[s]; }
            float r = 0.f;
            #pragma unroll
            for (int s = 0; s < 8; ++s) if (ti[s] == lane) r = (float)(e8[s] / s8);
            out[(size_t)gt * NX + lane] = r;
            if (lane < TK) out[TI_OFF + (size_t)gt * TK + lane] = (float)ti[lane];
        }
        __syncthreads();
    }
}

// ---------------------------------------------------------------------------
__global__ __launch_bounds__(64) void finalize_kernel(
    const float* __restrict__ ps_acc, const float* __restrict__ fr_acc,
    const float* __restrict__ lse2_acc, float* __restrict__ out)
{
    const int lane = threadIdx.x;
    float p = ps_acc[lane], f = fr_acc[lane];
    float sp = p, sf = f;
    #pragma unroll
    for (int off = 32; off > 0; off >>= 1) {
        sp += __shfl_xor(sp, off);
        sf += __shfl_xor(sf, off);
    }
    float d = (p / fmaxf(sp, 1e-12f)) * (f / fmaxf(sf, 1e-12f));
    #pragma unroll
    for (int off = 32; off > 0; off >>= 1) d += __shfl_xor(d, off);
    if (lane == 0)
        out[AUX_IDX] = 64.f * d + 0.1f * (lse2_acc[0] / (float)NT);
}

// ---------------------------------------------------------------------------
extern "C" void kernel_launch(void* const* d_in, const int* in_sizes, int n_in,
                              void* d_out, int out_size, void* d_ws, size_t ws_size,
                              hipStream_t stream) {
    const float* x       = (const float*)d_in[0];
    const float* w_route = (const float*)d_in[1];
    const float* b_route = (const float*)d_in[2];
    const float* w_noise = (const float*)d_in[3];
    const float* b_noise = (const float*)d_in[4];
    const float* noise   = (const float*)d_in[5];
    float* out = (float*)d_out;

    float* ps   = (float*)d_ws;
    float* fr   = ps + 64;
    float* lse2 = ps + 128;
    int* flag_cnt  = (int*)(ps + 129);
    int* flag_list = (int*)(ps + 130);

    hipMemsetAsync(d_ws, 0, (size_t)STATS_FLOATS * sizeof(float), stream);

    if (ws_size >= WS_NEED) {
        unsigned short* bpack = (unsigned short*)((char*)d_ws + BPACK_OFF);
        prep_w_kernel<<<128, 512, 0, stream>>>(w_route, w_noise, bpack);
        fused32_kernel<<<NBLK, 512, 0, stream>>>(
            x, bpack, b_route, b_noise, noise, out,
            ps, fr, lse2, flag_cnt, flag_list);
    } else {
        fused_router_kernel<<<NT / FBM, 256, 0, stream>>>(
            x, w_route, b_route, w_noise, b_noise, noise, out,
            ps, fr, lse2, flag_cnt, flag_list);
    }

    refine_kernel<<<1024, 256, 0, stream>>>(
        x, w_route, b_route, w_noise, b_noise, noise, out, flag_cnt, flag_list);

    finalize_kernel<<<1, 64, 0, stream>>>(ps, fr, lse2, out);
}